// Round 7
// baseline (257.599 us; speedup 1.0000x reference)
//
#include <hip/hip_runtime.h>
#include <stdint.h>

#define B_  16
#define C_  512
#define S_  1024
#define NSAMP (C_*S_)

typedef __bf16 bf16x8 __attribute__((ext_vector_type(8)));
typedef float  f32x4  __attribute__((ext_vector_type(4)));

__device__ __forceinline__ float bf2f(uint16_t u){ return __uint_as_float(((uint32_t)u)<<16); }
__device__ __forceinline__ uint16_t f2bf(float f){
  uint32_t u = __float_as_uint(f);
  uint32_t r = u + 0x7fffu + ((u>>16)&1u);   // RNE
  return (uint16_t)(r>>16);
}
__device__ __forceinline__ float wsum(float v){
  #pragma unroll
  for(int o=32;o;o>>=1) v += __shfl_xor(v,o,64);
  return v;
}
__device__ __forceinline__ void gload16(const void* g, void* l){
  __builtin_amdgcn_global_load_lds(
      (__attribute__((address_space(1))) void*)g,
      (__attribute__((address_space(3))) void*)l, 16, 0, 0);
}
__device__ __forceinline__ float loadp(const void* p, int i, int f){
  return f ? ((const float*)p)[i] : bf2f(((const uint16_t*)p)[i]);
}

// ---------- dtype detector ----------
__global__ __launch_bounds__(256) void detect_k(const uint16_t* __restrict__ x,
                                                int* __restrict__ flag){
  __shared__ int sh[4];
  int cnt = 0;
  for(int i=threadIdx.x; i<32768; i+=256){
    uint32_t e = (x[2*i] >> 7) & 0xffu;
    cnt += (e >= 132) ? 1 : 0;
  }
  #pragma unroll
  for(int o=32;o;o>>=1) cnt += __shfl_xor(cnt,o,64);
  const int lane = threadIdx.x & 63, w = threadIdx.x >> 6;
  if (lane==0) sh[w] = cnt;
  __syncthreads();
  if (threadIdx.x==0) *flag = (sh[0]+sh[1]+sh[2]+sh[3] > 4096) ? 1 : 0;  // 1 => fp32
}

// ---------- bf16 copy helper ----------
__device__ __forceinline__ void convseg(const void* src, uint16_t* dst, int n, int f, int t){
  const int idx = t*8;
  if (idx >= n) return;
  if (f){
    const float* s = (const float*)src;
    float4 v0 = *(const float4*)(s + idx);
    float4 v1 = *(const float4*)(s + idx + 4);
    ushort4 a, b;
    a.x=f2bf(v0.x); a.y=f2bf(v0.y); a.z=f2bf(v0.z); a.w=f2bf(v0.w);
    b.x=f2bf(v1.x); b.y=f2bf(v1.y); b.z=f2bf(v1.z); b.w=f2bf(v1.w);
    *(ushort4*)(dst + idx)     = a;
    *(ushort4*)(dst + idx + 4) = b;
  } else {
    *(uint4*)(dst + idx) = *(const uint4*)((const uint16_t*)src + idx);
  }
}

// ---------- mega-prep: x->(xb, xT, GN partials) | W2=W*gw | projw | biases | S1,S2 | zero rsum ----------
__global__ __launch_bounds__(256) void prep_k(
    const void* __restrict__ srcx, uint16_t* __restrict__ xb, uint16_t* __restrict__ xT,
    float2* __restrict__ part,
    const void* qkvw, const void* projw, const void* gnw, const void* gnb,
    const void* qkvb, const void* projb,
    uint16_t* qkvwb, uint16_t* projwb, uint16_t* qkvbb, uint16_t* projbb,
    float* __restrict__ S1f, float* __restrict__ S2f, float* __restrict__ rsum,
    const int* __restrict__ flag)
{
  __shared__ uint16_t tile[64][66];
  __shared__ float rs[4], rq[4];
  __shared__ float gws[512];
  const int f = *flag;
  const int t = threadIdx.x;
  const int bid = blockIdx.x;

  if (bid < 2048){
    // ---- x path: 64c x 64s tile of batch b ----
    const int b = bid >> 7, rem = bid & 127;
    const int c0 = (rem >> 4) << 6, s0 = (rem & 15) << 6;
    const int tc = t >> 6, tl = t & 63;
    float s = 0.f, s2 = 0.f;
    #pragma unroll
    for(int r=0;r<16;r++){
      const int cl = r*4 + tc;
      const size_t gi = ((size_t)b*C_ + c0+cl)*S_ + s0 + tl;
      float v; uint16_t h;
      if (f){ v = ((const float*)srcx)[gi]; h = f2bf(v); v = bf2f(h); }
      else  { h = ((const uint16_t*)srcx)[gi]; v = bf2f(h); }
      s += v; s2 += v*v;
      xb[gi] = h;
      tile[cl][tl] = h;
    }
    __syncthreads();
    #pragma unroll
    for(int r=0;r<16;r++){
      const int sl = r*4 + tc;
      xT[((size_t)b*S_ + s0+sl)*C_ + c0 + tl] = tile[tl][sl];
    }
    s = wsum(s); s2 = wsum(s2);
    const int lane = t & 63, w = t >> 6;
    if (lane==0){ rs[w]=s; rq[w]=s2; }
    __syncthreads();
    if (t==0) part[bid] = make_float2(rs[0]+rs[1]+rs[2]+rs[3], rq[0]+rq[1]+rq[2]+rq[3]);
    return;
  }
  if (bid < 2432){
    // ---- W2 = qkvw * gw[c], bf16 ----
    for(int i=t;i<512;i+=256) gws[i] = loadp(gnw, i, f);
    __syncthreads();
    const int off = (bid-2048)*2048;
    const int e = off + t*8;
    const int c = e & 511;
    float v[8];
    if (f){
      float4 a = *(const float4*)((const float*)qkvw + e);
      float4 bq = *(const float4*)((const float*)qkvw + e + 4);
      v[0]=a.x; v[1]=a.y; v[2]=a.z; v[3]=a.w; v[4]=bq.x; v[5]=bq.y; v[6]=bq.z; v[7]=bq.w;
    } else {
      uint4 a = *(const uint4*)((const uint16_t*)qkvw + e);
      uint32_t uu[4]={a.x,a.y,a.z,a.w};
      #pragma unroll
      for(int q=0;q<4;q++){ v[2*q]=__uint_as_float(uu[q]<<16); v[2*q+1]=__uint_as_float(uu[q]&0xffff0000u); }
    }
    ushort4 o0,o1;
    o0.x=f2bf(v[0]*gws[c+0]); o0.y=f2bf(v[1]*gws[c+1]); o0.z=f2bf(v[2]*gws[c+2]); o0.w=f2bf(v[3]*gws[c+3]);
    o1.x=f2bf(v[4]*gws[c+4]); o1.y=f2bf(v[5]*gws[c+5]); o1.z=f2bf(v[6]*gws[c+6]); o1.w=f2bf(v[7]*gws[c+7]);
    *(ushort4*)(qkvwb + e)   = o0;
    *(ushort4*)(qkvwb + e+4) = o1;
    return;
  }
  if (bid < 2560){
    const size_t off = (size_t)(bid-2432)*2048;
    convseg((const char*)projw + off*(f?4:2), projwb + off, 2048, f, t);
    return;
  }
  if (bid == 2560){
    convseg(qkvb,  qkvbb,  1536, f, t);
    convseg(projb, projbb, 512,  f, t);
    return;
  }
  if (bid < 2585){
    // ---- S1[o]=sum W*gb, S2[o]=sum W*gw; 64 rows per block, 4 threads/row ----
    const int L = bid - 2561;
    const int row = L*64 + (t>>2);
    const int cc0 = (t&3)*128;
    float s1=0.f, s2v=0.f;
    for(int z=0;z<128;z++){
      const int c = cc0 + z;
      const float wv = loadp(qkvw, row*512 + c, f);
      s1  += wv * loadp(gnb, c, f);
      s2v += wv * loadp(gnw, c, f);
    }
    s1  += __shfl_xor(s1,1,64);  s1  += __shfl_xor(s1,2,64);
    s2v += __shfl_xor(s2v,1,64); s2v += __shfl_xor(s2v,2,64);
    if ((t&3)==0){ S1f[row] = s1; S2f[row] = s2v; }
    return;
  }
  {
    // ---- zero rsum (16384 floats, 4 blocks) ----
    const int base = (bid-2585)*4096 + t*16;
    #pragma unroll
    for(int q=0;q<4;q++) *(float4*)(rsum + base + q*4) = (float4){0.f,0.f,0.f,0.f};
  }
}

// ======== merged QK + V^T GEMMs on xT, GN folded via (W2, S1, S2, stats) ========
// blocks 0..1023:  qk[s,o] = rstd_b*(xT . W2[0:1024]^T) + S1[o]+qkvb[o]-mu*rstd*S2[o]
// blocks 1024..1535: Vt[b][ch,key] = rstd_b*(W2v . xT_b^T) + (same bias, o=1024+ch)
__global__ __launch_bounds__(256)
void qkv_k(const uint16_t* __restrict__ xT, const uint16_t* __restrict__ W2,
           const uint16_t* __restrict__ qkvbb, const float2* __restrict__ part,
           const float* __restrict__ S1f, const float* __restrict__ S2f,
           uint16_t* __restrict__ qk, uint16_t* __restrict__ Vt)
{
  __shared__ uint16_t As[128*64];
  __shared__ uint16_t Bs[128*64];
  __shared__ float sred[8];
  const int tid = threadIdx.x;
  const int lane = tid & 63, w = tid >> 6;
  const int quad = lane >> 4, lm = lane & 15;
  const int wm = (w & 1) << 6, wn = (w >> 1) << 6;

  const bool vpath = blockIdx.x >= 1024;
  const int id = vpath ? (blockIdx.x - 1024) : blockIdx.x;
  const int r8 = id & 7, k8 = id >> 3;
  int m0, n0, bz, bb;
  const uint16_t *Abase, *Bbase;
  if (!vpath){
    const int g = r8*16 + (k8 & 15);        // by 0..127
    m0 = g << 7; n0 = (k8 >> 4) << 7; bz = 0;
    bb = m0 >> 10;
    Abase = xT + (size_t)m0*512;
    Bbase = W2 + (size_t)n0*512;
  } else {
    const int g = r8*16 + (k8 & 15);        // 0..127 -> (bx,bz)
    m0 = (k8 >> 4) << 7; n0 = (g & 7) << 7; bz = g >> 3;
    bb = bz;
    Abase = W2 + (size_t)(1024 + m0)*512;
    Bbase = xT + (size_t)bz*S_*C_ + (size_t)n0*512;
  }

  // per-batch GN stats from 128 partials
  {
    float2 pv = make_float2(0.f,0.f);
    if (tid < 128) pv = part[(size_t)bb*128 + tid];
    float ss = wsum(pv.x), ss2 = wsum(pv.y);
    if ((tid&63)==0){ sred[(tid>>6)*2] = ss; sred[(tid>>6)*2+1] = ss2; }
  }

  f32x4 acc[4][4];
  #pragma unroll
  for(int i=0;i<4;i++)
    #pragma unroll
    for(int j=0;j<4;j++) acc[i][j] = (f32x4){0.f,0.f,0.f,0.f};

  const int srow = tid >> 3;
  const int sx   = (tid & 7) ^ (srow & 7);
  const uint16_t* ga = Abase + (size_t)srow*512 + sx*8;
  const uint16_t* gb = Bbase + (size_t)srow*512 + sx*8;
  uint16_t* sa = &As[tid*8];
  uint16_t* sb = &Bs[tid*8];

  for(int k0=0;k0<512;k0+=64){
    #pragma unroll
    for(int i=0;i<4;i++){
      gload16(ga + (size_t)(i*32)*512 + k0, sa + i*2048);
      gload16(gb + (size_t)(i*32)*512 + k0, sb + i*2048);
    }
    __syncthreads();
    #pragma unroll
    for(int kk=0;kk<64;kk+=32){
      bf16x8 av[4], bv[4];
      #pragma unroll
      for(int i=0;i<4;i++){
        const int row = wm + i*16 + lm;
        av[i] = *(const bf16x8*)&As[row*64 + ((((kk>>3)+quad) ^ (row&7))<<3)];
      }
      #pragma unroll
      for(int j=0;j<4;j++){
        const int row = wn + j*16 + lm;
        bv[j] = *(const bf16x8*)&Bs[row*64 + ((((kk>>3)+quad) ^ (row&7))<<3)];
      }
      #pragma unroll
      for(int i=0;i<4;i++)
        #pragma unroll
        for(int j=0;j<4;j++)
          acc[i][j] = __builtin_amdgcn_mfma_f32_16x16x32_bf16(av[i], bv[j], acc[i][j], 0,0,0);
    }
    __syncthreads();
  }

  const float ssum  = sred[0]+sred[2]+sred[4]+sred[6];
  const float ssum2 = sred[1]+sred[3]+sred[5]+sred[7];
  const float ninv = 1.f/(float)NSAMP;
  const float mu = ssum*ninv;
  const float rstd = rsqrtf(ssum2*ninv - mu*mu + 1e-5f);
  const float mrs = mu*rstd;

  if (!vpath){
    #pragma unroll
    for(int j=0;j<4;j++){
      const int col = n0 + wn + j*16 + lm;
      const float cadd = S1f[col] + bf2f(qkvbb[col]) - mrs*S2f[col];
      #pragma unroll
      for(int i=0;i<4;i++){
        const int rb = m0 + wm + i*16 + (quad<<2);
        #pragma unroll
        for(int r=0;r<4;r++)
          qk[(size_t)(rb+r)*1024 + col] = f2bf(rstd*acc[i][j][r] + cadd);
      }
    }
  } else {
    uint16_t* vb = Vt + (size_t)bz*C_*S_;
    #pragma unroll
    for(int i=0;i<4;i++){
      const int rb = m0 + wm + i*16 + (quad<<2);
      #pragma unroll
      for(int r=0;r<4;r++){
        const int och = 1024 + rb + r;
        const float cadd = S1f[och] + bf2f(qkvbb[och]) - mrs*S2f[och];
        #pragma unroll
        for(int j=0;j<4;j++)
          vb[(size_t)(rb+r)*1024 + n0 + wn + j*16 + lm] = f2bf(rstd*acc[i][j][r] + cadd);
      }
    }
  }
}

// ---------------- 128x128 MFMA GEMM, C = A * Bt^T ----------------
// EXP: epilogue exp(scale*acc). RSATOM: atomicAdd per-row exp-sums into rsum.
// RSDIV: divide by rsum[row]. SWZMODE: XCD grouping (0: share A-rows; 1: share B-rows).
template<bool HASBIAS, bool BIASROW, bool OUTDYN, bool HASRES, int SWZMODE,
         bool EXP, bool RSATOM, bool RSDIV>
__global__ __launch_bounds__(256)
void gemm_bt(const uint16_t* __restrict__ A, const uint16_t* __restrict__ Bt,
             void* __restrict__ Cp, const uint16_t* __restrict__ bias,
             const uint16_t* __restrict__ xres, const int* __restrict__ flag,
             float* __restrict__ rsum,
             int lda, int ldb, int ldc, int K,
             long long sA, long long sB, long long sC)
{
  __shared__ uint16_t As[128*64];
  __shared__ uint16_t Bs[128*64];
  const int lin = (blockIdx.z * gridDim.y + blockIdx.y) * gridDim.x + blockIdx.x;
  const int r8 = lin & 7, kk8 = lin >> 3;
  int bx, by, bz;
  if (SWZMODE == 0){
    const int G = (gridDim.y * gridDim.z) >> 3;
    const int g = r8 * G + (kk8 % G);
    bx = kk8 / G; by = g % gridDim.y; bz = g / gridDim.y;
  } else {
    const int G = (gridDim.x * gridDim.z) >> 3;
    const int g = r8 * G + (kk8 % G);
    by = kk8 / G; bx = g % gridDim.x; bz = g / gridDim.x;
  }

  const int tid = threadIdx.x;
  const int lane = tid & 63, w = tid >> 6;
  const int quad = lane >> 4, lm = lane & 15;
  const int m0 = by << 7, n0 = bx << 7;
  A  += (size_t)bz * sA;
  Bt += (size_t)bz * sB;

  f32x4 acc[4][4];
  #pragma unroll
  for(int i=0;i<4;i++)
    #pragma unroll
    for(int j=0;j<4;j++) acc[i][j] = (f32x4){0.f,0.f,0.f,0.f};

  const int wm = (w & 1) << 6, wn = (w >> 1) << 6;
  const int srow = tid >> 3;
  const int sx   = (tid & 7) ^ (srow & 7);
  const uint16_t* ga = A  + (size_t)(m0 + srow)*lda + sx*8;
  const uint16_t* gb = Bt + (size_t)(n0 + srow)*ldb + sx*8;
  uint16_t* sa = &As[tid*8];
  uint16_t* sb = &Bs[tid*8];

  for(int k0=0;k0<K;k0+=64){
    #pragma unroll
    for(int i=0;i<4;i++){
      gload16(ga + (size_t)(i*32)*lda + k0, sa + i*2048);
      gload16(gb + (size_t)(i*32)*ldb + k0, sb + i*2048);
    }
    __syncthreads();
    #pragma unroll
    for(int kk=0;kk<64;kk+=32){
      bf16x8 av[4], bv[4];
      #pragma unroll
      for(int i=0;i<4;i++){
        const int row = wm + i*16 + lm;
        av[i] = *(const bf16x8*)&As[row*64 + ((((kk>>3)+quad) ^ (row&7))<<3)];
      }
      #pragma unroll
      for(int j=0;j<4;j++){
        const int row = wn + j*16 + lm;
        bv[j] = *(const bf16x8*)&Bs[row*64 + ((((kk>>3)+quad) ^ (row&7))<<3)];
      }
      #pragma unroll
      for(int i=0;i<4;i++)
        #pragma unroll
        for(int j=0;j<4;j++)
          acc[i][j] = __builtin_amdgcn_mfma_f32_16x16x32_bf16(av[i], bv[j], acc[i][j], 0,0,0);
    }
    __syncthreads();
  }

  const int f = OUTDYN ? *flag : 0;
  const size_t cb = (size_t)bz * (size_t)sC;
  float inv_[4][4];
  if (RSDIV){
    #pragma unroll
    for(int i=0;i<4;i++)
      #pragma unroll
      for(int r=0;r<4;r++)
        inv_[i][r] = 1.f / rsum[(size_t)bz*1024 + m0 + wm + i*16 + (quad<<2) + r];
  }
  float rloc[4][4];
  if (RSATOM){
    #pragma unroll
    for(int i=0;i<4;i++)
      #pragma unroll
      for(int r=0;r<4;r++) rloc[i][r] = 0.f;
  }
  #pragma unroll
  for(int j=0;j<4;j++){
    const int col = n0 + wn + j*16 + lm;
    const float cbias = (HASBIAS && !BIASROW) ? bf2f(bias[col]) : 0.f;
    #pragma unroll
    for(int i=0;i<4;i++){
      const int rb = m0 + wm + i*16 + (quad<<2);
      #pragma unroll
      for(int r=0;r<4;r++){
        const int row = rb + r;
        float v = acc[i][j][r] + cbias;
        if (HASBIAS && BIASROW) v += bf2f(bias[row]);
        if (EXP)   v = __expf(v * 0.044194173824159216f);   // 512^-0.5
        if (RSATOM) rloc[i][r] += v;
        if (RSDIV) v *= inv_[i][r];
        const size_t idx = cb + (size_t)row*ldc + col;
        if (HASRES) v += bf2f(xres[idx]);
        if (OUTDYN && f) ((float*)Cp)[idx] = v;
        else             ((uint16_t*)Cp)[idx] = f2bf(v);
      }
    }
  }
  if (RSATOM){
    #pragma unroll
    for(int o=1;o<16;o<<=1)
      #pragma unroll
      for(int i=0;i<4;i++)
        #pragma unroll
        for(int r=0;r<4;r++) rloc[i][r] += __shfl_xor(rloc[i][r], o, 64);
    if (lm==0){
      #pragma unroll
      for(int i=0;i<4;i++)
        #pragma unroll
        for(int r=0;r<4;r++)
          atomicAdd(&rsum[(size_t)bz*1024 + m0 + wm + i*16 + (quad<<2) + r], rloc[i][r]);
    }
  }
}

extern "C" void kernel_launch(void* const* d_in, const int* in_sizes, int n_in,
                              void* d_out, int out_size, void* d_ws, size_t ws_size,
                              hipStream_t stream){
  char* ws = (char*)d_ws;
  int*      flag  = (int*)ws;                         // 4 B
  float2*   part  = (float2*)(ws + 4096);             // 16 KB (2048 float2)
  float*    S1f   = (float*)(ws + 20480);             // 6 KB
  float*    S2f   = (float*)(ws + 26624);             // 6 KB
  float*    rsum  = (float*)(ws + 32768);             // 64 KB
  uint16_t* qkvbb = (uint16_t*)(ws + 98304);
  uint16_t* projbb= (uint16_t*)(ws + 101376);
  uint16_t* qkvwb = (uint16_t*)(ws + 131072);         // 1.57 MB (W2 = W*gw)
  uint16_t* projwb= (uint16_t*)(ws + 1703936);        // 0.52 MB
  uint16_t* xb    = (uint16_t*)(ws + 4194304);        // 16.8 MB [B,C,S]
  uint16_t* xT    = (uint16_t*)(ws + 20971520);       // 16.8 MB [16384,512]
  uint16_t* attn  = (uint16_t*)(ws + 37748736);       // 16.8 MB [16384,512]
  uint16_t* qk    = (uint16_t*)(ws + 54525952);       // 33.6 MB [16384,1024] (Q|K)
  uint16_t* sc    = (uint16_t*)(ws + 88080384);       // 33.6 MB [16,1024,1024] P'
  uint16_t* Vt    = (uint16_t*)(ws + 121634816);      // 16.8 MB [16,512,1024]
  // end ~138 MB

  hipLaunchKernelGGL(detect_k, dim3(1), dim3(256), 0, stream,
                     (const uint16_t*)d_in[0], flag);
  hipLaunchKernelGGL(prep_k, dim3(2589), dim3(256), 0, stream,
                     d_in[0], xb, xT, part,
                     d_in[3], d_in[5], d_in[1], d_in[2], d_in[4], d_in[6],
                     qkvwb, projwb, qkvbb, projbb, S1f, S2f, rsum, flag);

  // merged QK + V^T on xT with GN folded
  hipLaunchKernelGGL(qkv_k, dim3(1536), dim3(256), 0, stream,
                     xT, qkvwb, qkvbb, part, S1f, S2f, qk, Vt);

  // P' = exp(scale * Q K^T) (bf16) + per-row exp-sum atomics
  hipLaunchKernelGGL((gemm_bt<false,false,false,false,0,true,true,false>),
      dim3(8,8,16), dim3(256), 0, stream,
      qk, qk + 512, (void*)sc, (const uint16_t*)nullptr, (const uint16_t*)nullptr, flag, rsum,
      1024, 1024, 1024, 512, (long long)S_*1024, (long long)S_*1024, (long long)S_*S_);

  // attn = (P' V) / rowsum: per batch [1024,1024] x [512,1024]^T
  hipLaunchKernelGGL((gemm_bt<false,false,false,false,0,false,false,true>),
      dim3(4,8,16), dim3(256), 0, stream,
      sc, Vt, (void*)attn, (const uint16_t*)nullptr, (const uint16_t*)nullptr, flag, rsum,
      1024, 1024, 512, 1024, (long long)S_*S_, (long long)C_*S_, (long long)S_*C_);

  // out[b,c,s] = projW · attn_b^T + projb + x
  hipLaunchKernelGGL((gemm_bt<true,true,true,true,1,false,false,false>),
      dim3(8,4,16), dim3(256), 0, stream,
      projwb, attn, d_out, projbb, xb, flag, (float*)nullptr,
      512, 512, 1024, 512, 0LL, (long long)S_*C_, (long long)C_*S_);
}

// Round 8
// 254.934 us; speedup vs baseline: 1.0105x; 1.0105x over previous
//
#include <hip/hip_runtime.h>
#include <stdint.h>

#define B_  16
#define C_  512
#define S_  1024
#define NSAMP (C_*S_)

typedef __bf16 bf16x8 __attribute__((ext_vector_type(8)));
typedef float  f32x4  __attribute__((ext_vector_type(4)));

__device__ __forceinline__ float bf2f(uint16_t u){ return __uint_as_float(((uint32_t)u)<<16); }
__device__ __forceinline__ uint16_t f2bf(float f){
  uint32_t u = __float_as_uint(f);
  uint32_t r = u + 0x7fffu + ((u>>16)&1u);   // RNE
  return (uint16_t)(r>>16);
}
__device__ __forceinline__ float wsum(float v){
  #pragma unroll
  for(int o=32;o;o>>=1) v += __shfl_xor(v,o,64);
  return v;
}
__device__ __forceinline__ void gload16(const void* g, void* l){
  __builtin_amdgcn_global_load_lds(
      (__attribute__((address_space(1))) void*)g,
      (__attribute__((address_space(3))) void*)l, 16, 0, 0);
}
__device__ __forceinline__ float loadp(const void* p, int i, int f){
  return f ? ((const float*)p)[i] : bf2f(((const uint16_t*)p)[i]);
}

// ---------- dtype detector ----------
__global__ __launch_bounds__(256) void detect_k(const uint16_t* __restrict__ x,
                                                int* __restrict__ flag){
  __shared__ int sh[4];
  int cnt = 0;
  for(int i=threadIdx.x; i<32768; i+=256){
    uint32_t e = (x[2*i] >> 7) & 0xffu;
    cnt += (e >= 132) ? 1 : 0;
  }
  #pragma unroll
  for(int o=32;o;o>>=1) cnt += __shfl_xor(cnt,o,64);
  const int lane = threadIdx.x & 63, w = threadIdx.x >> 6;
  if (lane==0) sh[w] = cnt;
  __syncthreads();
  if (threadIdx.x==0) *flag = (sh[0]+sh[1]+sh[2]+sh[3] > 4096) ? 1 : 0;  // 1 => fp32
}

// ---------- bf16 copy helper ----------
__device__ __forceinline__ void convseg(const void* src, uint16_t* dst, int n, int f, int t){
  const int idx = t*8;
  if (idx >= n) return;
  if (f){
    const float* s = (const float*)src;
    float4 v0 = *(const float4*)(s + idx);
    float4 v1 = *(const float4*)(s + idx + 4);
    ushort4 a, b;
    a.x=f2bf(v0.x); a.y=f2bf(v0.y); a.z=f2bf(v0.z); a.w=f2bf(v0.w);
    b.x=f2bf(v1.x); b.y=f2bf(v1.y); b.z=f2bf(v1.z); b.w=f2bf(v1.w);
    *(ushort4*)(dst + idx)     = a;
    *(ushort4*)(dst + idx + 4) = b;
  } else {
    *(uint4*)(dst + idx) = *(const uint4*)((const uint16_t*)src + idx);
  }
}

// ---------- mega-prep (all 16B/lane vectorized) ----------
// blocks 0..2047:   x -> (xb if fp32, xT transpose, GN partials), 64c x 64s tiles via LDS
// blocks 2048..2431: W2 = qkvw * gw[c]
// 2432..2559: projw copy; 2560: biases; 2561..2584: S1,S2; 2585..2588: zero rsum
__global__ __launch_bounds__(256) void prep_k(
    const void* __restrict__ srcx, uint16_t* __restrict__ xb, uint16_t* __restrict__ xT,
    float2* __restrict__ part,
    const void* qkvw, const void* projw, const void* gnw, const void* gnb,
    const void* qkvb, const void* projb,
    uint16_t* qkvwb, uint16_t* projwb, uint16_t* qkvbb, uint16_t* projbb,
    float* __restrict__ S1f, float* __restrict__ S2f, float* __restrict__ rsum,
    const int* __restrict__ flag)
{
  __shared__ uint16_t tile[64][65];   // pad 65: transpose gather hits banks 4k%32
  __shared__ float rs[4], rq[4];
  __shared__ float gws[512];
  const int f = *flag;
  const int t = threadIdx.x;
  const int bid = blockIdx.x;

  if (bid < 2048){
    const int b = bid >> 7, rem = bid & 127;
    const int c0 = (rem >> 4) << 6, s0 = (rem & 15) << 6;
    const int rr = t >> 3;          // 0..31
    const int cc = (t & 7) * 8;     // 0..56
    float s = 0.f, s2 = 0.f;
    #pragma unroll
    for(int it=0; it<2; it++){
      const int cl = it*32 + rr;
      const size_t gi = ((size_t)b*C_ + c0+cl)*S_ + s0 + cc;
      uint16_t h[8];
      if (f){
        float4 v0 = *(const float4*)((const float*)srcx + gi);
        float4 v1 = *(const float4*)((const float*)srcx + gi + 4);
        float vv[8] = {v0.x,v0.y,v0.z,v0.w,v1.x,v1.y,v1.z,v1.w};
        #pragma unroll
        for(int z=0;z<8;z++){ s += vv[z]; s2 += vv[z]*vv[z]; h[z] = f2bf(vv[z]); }
        ushort4 o0, o1;
        o0.x=h[0]; o0.y=h[1]; o0.z=h[2]; o0.w=h[3];
        o1.x=h[4]; o1.y=h[5]; o1.z=h[6]; o1.w=h[7];
        *(ushort4*)(xb + gi)     = o0;
        *(ushort4*)(xb + gi + 4) = o1;
      } else {
        uint4 p = *(const uint4*)((const uint16_t*)srcx + gi);
        uint32_t uu[4]={p.x,p.y,p.z,p.w};
        #pragma unroll
        for(int q=0;q<4;q++){
          h[2*q]   = (uint16_t)(uu[q] & 0xffffu);
          h[2*q+1] = (uint16_t)(uu[q] >> 16);
          float f0 = bf2f(h[2*q]), f1 = bf2f(h[2*q+1]);
          s += f0 + f1; s2 += f0*f0 + f1*f1;
        }
      }
      #pragma unroll
      for(int z=0;z<8;z++) tile[cl][cc+z] = h[z];
    }
    __syncthreads();
    #pragma unroll
    for(int it=0; it<2; it++){
      const int sl = it*32 + rr;
      ushort4 o0, o1;
      o0.x=tile[cc+0][sl]; o0.y=tile[cc+1][sl]; o0.z=tile[cc+2][sl]; o0.w=tile[cc+3][sl];
      o1.x=tile[cc+4][sl]; o1.y=tile[cc+5][sl]; o1.z=tile[cc+6][sl]; o1.w=tile[cc+7][sl];
      const size_t go = ((size_t)b*S_ + s0+sl)*C_ + c0 + cc;
      *(ushort4*)(xT + go)     = o0;
      *(ushort4*)(xT + go + 4) = o1;
    }
    s = wsum(s); s2 = wsum(s2);
    const int lane = t & 63, w = t >> 6;
    if (lane==0){ rs[w]=s; rq[w]=s2; }
    __syncthreads();
    if (t==0) part[bid] = make_float2(rs[0]+rs[1]+rs[2]+rs[3], rq[0]+rq[1]+rq[2]+rq[3]);
    return;
  }
  if (bid < 2432){
    // ---- W2 = qkvw * gw[c], bf16 ----
    for(int i=t;i<512;i+=256) gws[i] = loadp(gnw, i, f);
    __syncthreads();
    const int off = (bid-2048)*2048;
    const int e = off + t*8;
    const int c = e & 511;
    float v[8];
    if (f){
      float4 a = *(const float4*)((const float*)qkvw + e);
      float4 bq = *(const float4*)((const float*)qkvw + e + 4);
      v[0]=a.x; v[1]=a.y; v[2]=a.z; v[3]=a.w; v[4]=bq.x; v[5]=bq.y; v[6]=bq.z; v[7]=bq.w;
    } else {
      uint4 a = *(const uint4*)((const uint16_t*)qkvw + e);
      uint32_t uu[4]={a.x,a.y,a.z,a.w};
      #pragma unroll
      for(int q=0;q<4;q++){ v[2*q]=__uint_as_float(uu[q]<<16); v[2*q+1]=__uint_as_float(uu[q]&0xffff0000u); }
    }
    ushort4 o0,o1;
    o0.x=f2bf(v[0]*gws[c+0]); o0.y=f2bf(v[1]*gws[c+1]); o0.z=f2bf(v[2]*gws[c+2]); o0.w=f2bf(v[3]*gws[c+3]);
    o1.x=f2bf(v[4]*gws[c+4]); o1.y=f2bf(v[5]*gws[c+5]); o1.z=f2bf(v[6]*gws[c+6]); o1.w=f2bf(v[7]*gws[c+7]);
    *(ushort4*)(qkvwb + e)   = o0;
    *(ushort4*)(qkvwb + e+4) = o1;
    return;
  }
  if (bid < 2560){
    const size_t off = (size_t)(bid-2432)*2048;
    convseg((const char*)projw + off*(f?4:2), projwb + off, 2048, f, t);
    return;
  }
  if (bid == 2560){
    convseg(qkvb,  qkvbb,  1536, f, t);
    convseg(projb, projbb, 512,  f, t);
    return;
  }
  if (bid < 2585){
    // ---- S1[o]=sum W*gb, S2[o]=sum W*gw; 64 rows per block, 4 threads/row ----
    const int L = bid - 2561;
    const int row = L*64 + (t>>2);
    const int cc0 = (t&3)*128;
    float s1=0.f, s2v=0.f;
    for(int z=0;z<128;z++){
      const int c = cc0 + z;
      const float wv = loadp(qkvw, row*512 + c, f);
      s1  += wv * loadp(gnb, c, f);
      s2v += wv * loadp(gnw, c, f);
    }
    s1  += __shfl_xor(s1,1,64);  s1  += __shfl_xor(s1,2,64);
    s2v += __shfl_xor(s2v,1,64); s2v += __shfl_xor(s2v,2,64);
    if ((t&3)==0){ S1f[row] = s1; S2f[row] = s2v; }
    return;
  }
  {
    // ---- zero rsum (16384 floats, 4 blocks) ----
    const int base = (bid-2585)*4096 + t*16;
    #pragma unroll
    for(int q=0;q<4;q++) *(float4*)(rsum + base + q*4) = (float4){0.f,0.f,0.f,0.f};
  }
}

// ======== merged QK + V^T GEMMs on xT, GN folded via (W2, S1, S2, stats) ========
__global__ __launch_bounds__(256)
void qkv_k(const uint16_t* __restrict__ xT, const uint16_t* __restrict__ W2,
           const uint16_t* __restrict__ qkvbb, const float2* __restrict__ part,
           const float* __restrict__ S1f, const float* __restrict__ S2f,
           uint16_t* __restrict__ qk, uint16_t* __restrict__ Vt)
{
  __shared__ uint16_t As[128*64];
  __shared__ uint16_t Bs[128*64];
  __shared__ float sred[8];
  const int tid = threadIdx.x;
  const int lane = tid & 63, w = tid >> 6;
  const int quad = lane >> 4, lm = lane & 15;
  const int wm = (w & 1) << 6, wn = (w >> 1) << 6;

  const bool vpath = blockIdx.x >= 1024;
  const int id = vpath ? (blockIdx.x - 1024) : blockIdx.x;
  const int r8 = id & 7, k8 = id >> 3;
  int m0, n0, bz, bb;
  const uint16_t *Abase, *Bbase;
  if (!vpath){
    const int g = r8*16 + (k8 & 15);        // by 0..127
    m0 = g << 7; n0 = (k8 >> 4) << 7; bz = 0;
    bb = m0 >> 10;
    Abase = xT + (size_t)m0*512;
    Bbase = W2 + (size_t)n0*512;
  } else {
    const int g = r8*16 + (k8 & 15);        // 0..127 -> (bx,bz)
    m0 = (k8 >> 4) << 7; n0 = (g & 7) << 7; bz = g >> 3;
    bb = bz;
    Abase = W2 + (size_t)(1024 + m0)*512;
    Bbase = xT + (size_t)bz*S_*C_ + (size_t)n0*512;
  }

  {
    float2 pv = make_float2(0.f,0.f);
    if (tid < 128) pv = part[(size_t)bb*128 + tid];
    float ss = wsum(pv.x), ss2 = wsum(pv.y);
    if ((tid&63)==0){ sred[(tid>>6)*2] = ss; sred[(tid>>6)*2+1] = ss2; }
  }

  f32x4 acc[4][4];
  #pragma unroll
  for(int i=0;i<4;i++)
    #pragma unroll
    for(int j=0;j<4;j++) acc[i][j] = (f32x4){0.f,0.f,0.f,0.f};

  const int srow = tid >> 3;
  const int sx   = (tid & 7) ^ (srow & 7);
  const uint16_t* ga = Abase + (size_t)srow*512 + sx*8;
  const uint16_t* gb = Bbase + (size_t)srow*512 + sx*8;
  uint16_t* sa = &As[tid*8];
  uint16_t* sb = &Bs[tid*8];

  for(int k0=0;k0<512;k0+=64){
    #pragma unroll
    for(int i=0;i<4;i++){
      gload16(ga + (size_t)(i*32)*512 + k0, sa + i*2048);
      gload16(gb + (size_t)(i*32)*512 + k0, sb + i*2048);
    }
    __syncthreads();
    #pragma unroll
    for(int kk=0;kk<64;kk+=32){
      bf16x8 av[4], bv[4];
      #pragma unroll
      for(int i=0;i<4;i++){
        const int row = wm + i*16 + lm;
        av[i] = *(const bf16x8*)&As[row*64 + ((((kk>>3)+quad) ^ (row&7))<<3)];
      }
      #pragma unroll
      for(int j=0;j<4;j++){
        const int row = wn + j*16 + lm;
        bv[j] = *(const bf16x8*)&Bs[row*64 + ((((kk>>3)+quad) ^ (row&7))<<3)];
      }
      #pragma unroll
      for(int i=0;i<4;i++)
        #pragma unroll
        for(int j=0;j<4;j++)
          acc[i][j] = __builtin_amdgcn_mfma_f32_16x16x32_bf16(av[i], bv[j], acc[i][j], 0,0,0);
    }
    __syncthreads();
  }

  const float ssum  = sred[0]+sred[2]+sred[4]+sred[6];
  const float ssum2 = sred[1]+sred[3]+sred[5]+sred[7];
  const float ninv = 1.f/(float)NSAMP;
  const float mu = ssum*ninv;
  const float rstd = rsqrtf(ssum2*ninv - mu*mu + 1e-5f);
  const float mrs = mu*rstd;

  if (!vpath){
    #pragma unroll
    for(int j=0;j<4;j++){
      const int col = n0 + wn + j*16 + lm;
      const float cadd = S1f[col] + bf2f(qkvbb[col]) - mrs*S2f[col];
      #pragma unroll
      for(int i=0;i<4;i++){
        const int rb = m0 + wm + i*16 + (quad<<2);
        #pragma unroll
        for(int r=0;r<4;r++)
          qk[(size_t)(rb+r)*1024 + col] = f2bf(rstd*acc[i][j][r] + cadd);
      }
    }
  } else {
    uint16_t* vb = Vt + (size_t)bz*C_*S_;
    #pragma unroll
    for(int i=0;i<4;i++){
      const int rb = m0 + wm + i*16 + (quad<<2);
      #pragma unroll
      for(int r=0;r<4;r++){
        const int och = 1024 + rb + r;
        const float cadd = S1f[och] + bf2f(qkvbb[och]) - mrs*S2f[och];
        #pragma unroll
        for(int j=0;j<4;j++)
          vb[(size_t)(rb+r)*1024 + n0 + wn + j*16 + lm] = f2bf(rstd*acc[i][j][r] + cadd);
      }
    }
  }
}

// ---------------- 128x128 MFMA GEMM, C = A * Bt^T ----------------
// EXP: epilogue exp(scale*acc). RSATOM: atomicAdd per-row exp-sums into rsum.
// RSDIV: divide by rsum[row]. HASRES: += residual from (f ? xres : xres2).
template<bool HASBIAS, bool BIASROW, bool OUTDYN, bool HASRES, int SWZMODE,
         bool EXP, bool RSATOM, bool RSDIV>
__global__ __launch_bounds__(256)
void gemm_bt(const uint16_t* __restrict__ A, const uint16_t* __restrict__ Bt,
             void* __restrict__ Cp, const uint16_t* __restrict__ bias,
             const uint16_t* __restrict__ xres, const uint16_t* __restrict__ xres2,
             const int* __restrict__ flag, float* __restrict__ rsum,
             int lda, int ldb, int ldc, int K,
             long long sA, long long sB, long long sC)
{
  __shared__ uint16_t As[128*64];
  __shared__ uint16_t Bs[128*64];
  const int lin = (blockIdx.z * gridDim.y + blockIdx.y) * gridDim.x + blockIdx.x;
  const int r8 = lin & 7, kk8 = lin >> 3;
  int bx, by, bz;
  if (SWZMODE == 0){
    const int G = (gridDim.y * gridDim.z) >> 3;
    const int g = r8 * G + (kk8 % G);
    bx = kk8 / G; by = g % gridDim.y; bz = g / gridDim.y;
  } else {
    const int G = (gridDim.x * gridDim.z) >> 3;
    const int g = r8 * G + (kk8 % G);
    by = kk8 / G; bx = g % gridDim.x; bz = g / gridDim.x;
  }

  const int tid = threadIdx.x;
  const int lane = tid & 63, w = tid >> 6;
  const int quad = lane >> 4, lm = lane & 15;
  const int m0 = by << 7, n0 = bx << 7;
  A  += (size_t)bz * sA;
  Bt += (size_t)bz * sB;

  f32x4 acc[4][4];
  #pragma unroll
  for(int i=0;i<4;i++)
    #pragma unroll
    for(int j=0;j<4;j++) acc[i][j] = (f32x4){0.f,0.f,0.f,0.f};

  const int wm = (w & 1) << 6, wn = (w >> 1) << 6;
  const int srow = tid >> 3;
  const int sx   = (tid & 7) ^ (srow & 7);
  const uint16_t* ga = A  + (size_t)(m0 + srow)*lda + sx*8;
  const uint16_t* gb = Bt + (size_t)(n0 + srow)*ldb + sx*8;
  uint16_t* sa = &As[tid*8];
  uint16_t* sb = &Bs[tid*8];

  for(int k0=0;k0<K;k0+=64){
    #pragma unroll
    for(int i=0;i<4;i++){
      gload16(ga + (size_t)(i*32)*lda + k0, sa + i*2048);
      gload16(gb + (size_t)(i*32)*ldb + k0, sb + i*2048);
    }
    __syncthreads();
    #pragma unroll
    for(int kk=0;kk<64;kk+=32){
      bf16x8 av[4], bv[4];
      #pragma unroll
      for(int i=0;i<4;i++){
        const int row = wm + i*16 + lm;
        av[i] = *(const bf16x8*)&As[row*64 + ((((kk>>3)+quad) ^ (row&7))<<3)];
      }
      #pragma unroll
      for(int j=0;j<4;j++){
        const int row = wn + j*16 + lm;
        bv[j] = *(const bf16x8*)&Bs[row*64 + ((((kk>>3)+quad) ^ (row&7))<<3)];
      }
      #pragma unroll
      for(int i=0;i<4;i++)
        #pragma unroll
        for(int j=0;j<4;j++)
          acc[i][j] = __builtin_amdgcn_mfma_f32_16x16x32_bf16(av[i], bv[j], acc[i][j], 0,0,0);
    }
    __syncthreads();
  }

  const int f = OUTDYN ? *flag : 0;
  const uint16_t* xr = HASRES ? (f ? xres : xres2) : (const uint16_t*)nullptr;
  const size_t cb = (size_t)bz * (size_t)sC;
  float inv_[4][4];
  if (RSDIV){
    #pragma unroll
    for(int i=0;i<4;i++)
      #pragma unroll
      for(int r=0;r<4;r++)
        inv_[i][r] = 1.f / rsum[(size_t)bz*1024 + m0 + wm + i*16 + (quad<<2) + r];
  }
  float rloc[4][4];
  if (RSATOM){
    #pragma unroll
    for(int i=0;i<4;i++)
      #pragma unroll
      for(int r=0;r<4;r++) rloc[i][r] = 0.f;
  }
  #pragma unroll
  for(int j=0;j<4;j++){
    const int col = n0 + wn + j*16 + lm;
    const float cbias = (HASBIAS && !BIASROW) ? bf2f(bias[col]) : 0.f;
    #pragma unroll
    for(int i=0;i<4;i++){
      const int rb = m0 + wm + i*16 + (quad<<2);
      #pragma unroll
      for(int r=0;r<4;r++){
        const int row = rb + r;
        float v = acc[i][j][r] + cbias;
        if (HASBIAS && BIASROW) v += bf2f(bias[row]);
        if (EXP)   v = __expf(v * 0.044194173824159216f);   // 512^-0.5
        if (RSATOM) rloc[i][r] += v;
        if (RSDIV) v *= inv_[i][r];
        const size_t idx = cb + (size_t)row*ldc + col;
        if (HASRES) v += bf2f(xr[idx]);
        if (OUTDYN && f) ((float*)Cp)[idx] = v;
        else             ((uint16_t*)Cp)[idx] = f2bf(v);
      }
    }
  }
  if (RSATOM){
    #pragma unroll
    for(int o=1;o<16;o<<=1)
      #pragma unroll
      for(int i=0;i<4;i++)
        #pragma unroll
        for(int r=0;r<4;r++) rloc[i][r] += __shfl_xor(rloc[i][r], o, 64);
    if (lm==0){
      #pragma unroll
      for(int i=0;i<4;i++)
        #pragma unroll
        for(int r=0;r<4;r++)
          atomicAdd(&rsum[(size_t)bz*1024 + m0 + wm + i*16 + (quad<<2) + r], rloc[i][r]);
    }
  }
}

extern "C" void kernel_launch(void* const* d_in, const int* in_sizes, int n_in,
                              void* d_out, int out_size, void* d_ws, size_t ws_size,
                              hipStream_t stream){
  char* ws = (char*)d_ws;
  int*      flag  = (int*)ws;                         // 4 B
  float2*   part  = (float2*)(ws + 4096);             // 16 KB (2048 float2)
  float*    S1f   = (float*)(ws + 20480);             // 6 KB
  float*    S2f   = (float*)(ws + 26624);             // 6 KB
  float*    rsum  = (float*)(ws + 32768);             // 64 KB
  uint16_t* qkvbb = (uint16_t*)(ws + 98304);
  uint16_t* projbb= (uint16_t*)(ws + 101376);
  uint16_t* qkvwb = (uint16_t*)(ws + 131072);         // 1.57 MB (W2 = W*gw)
  uint16_t* projwb= (uint16_t*)(ws + 1703936);        // 0.52 MB
  uint16_t* xb    = (uint16_t*)(ws + 4194304);        // 16.8 MB [B,C,S] (only used if fp32 in)
  uint16_t* xT    = (uint16_t*)(ws + 20971520);       // 16.8 MB [16384,512]
  uint16_t* attn  = (uint16_t*)(ws + 37748736);       // 16.8 MB [16384,512]
  uint16_t* qk    = (uint16_t*)(ws + 54525952);       // 33.6 MB [16384,1024] (Q|K)
  uint16_t* sc    = (uint16_t*)(ws + 88080384);       // 33.6 MB [16,1024,1024] P'
  uint16_t* Vt    = (uint16_t*)(ws + 121634816);      // 16.8 MB [16,512,1024]
  // end ~138 MB

  hipLaunchKernelGGL(detect_k, dim3(1), dim3(256), 0, stream,
                     (const uint16_t*)d_in[0], flag);
  hipLaunchKernelGGL(prep_k, dim3(2589), dim3(256), 0, stream,
                     d_in[0], xb, xT, part,
                     d_in[3], d_in[5], d_in[1], d_in[2], d_in[4], d_in[6],
                     qkvwb, projwb, qkvbb, projbb, S1f, S2f, rsum, flag);

  // merged QK + V^T on xT with GN folded
  hipLaunchKernelGGL(qkv_k, dim3(1536), dim3(256), 0, stream,
                     xT, qkvwb, qkvbb, part, S1f, S2f, qk, Vt);

  // P' = exp(scale * Q K^T) (bf16) + per-row exp-sum atomics
  hipLaunchKernelGGL((gemm_bt<false,false,false,false,0,true,true,false>),
      dim3(8,8,16), dim3(256), 0, stream,
      qk, qk + 512, (void*)sc, (const uint16_t*)nullptr,
      (const uint16_t*)nullptr, (const uint16_t*)nullptr, flag, rsum,
      1024, 1024, 1024, 512, (long long)S_*1024, (long long)S_*1024, (long long)S_*S_);

  // attn = (P' V) / rowsum: per batch [1024,1024] x [512,1024]^T
  hipLaunchKernelGGL((gemm_bt<false,false,false,false,0,false,false,true>),
      dim3(4,8,16), dim3(256), 0, stream,
      sc, Vt, (void*)attn, (const uint16_t*)nullptr,
      (const uint16_t*)nullptr, (const uint16_t*)nullptr, flag, rsum,
      1024, 1024, 512, 1024, (long long)S_*S_, (long long)C_*S_, (long long)S_*C_);

  // out[b,c,s] = projW · attn_b^T + projb + x   (residual from xb if fp32 else d_in[0])
  hipLaunchKernelGGL((gemm_bt<true,true,true,true,1,false,false,false>),
      dim3(8,4,16), dim3(256), 0, stream,
      projwb, attn, d_out, projbb, xb, (const uint16_t*)d_in[0], flag, rsum,
      512, 512, 1024, 512, 0LL, (long long)S_*C_, (long long)C_*S_);
}